// Round 9
// baseline (235.924 us; speedup 1.0000x reference)
//
#include <hip/hip_runtime.h>
#include <hip/hip_bf16.h>

// Fused QKV projection + 16-head self-attention. S=2048, B=2, H=1024, NH=16, DH=64.
// Inputs fp32, output fp32. bf16 internal compute (2% rel threshold).
//
// R9: key-split attention. R8 was at its LDS-throughput floor (~96KB LDS per
// block-kt, 61us floor vs 72.5 measured); the 64KB of redundant K/V fragment
// re-reads (4 waves x same tile) is removed by splitting KEYS across waves —
// legal with zero sync because no-max softmax partials are linear (l,O sums).
// K/V frags now load global->reg directly (L2-served); LDS only for the
// wave-private P transpose + one-shot merge. No barriers in the k-loop.
//
// d_ws: qb[hb][s][d] 8MB | kb[hb][s][d] 8MB | vtb[hb][d][s] 8MB  (hb = h*2+b)

typedef __hip_bfloat16 bf16;
typedef __bf16 bfr;
typedef __attribute__((ext_vector_type(8))) __bf16 bf16x8;
typedef __attribute__((ext_vector_type(4))) __bf16 bf16x4;
typedef __attribute__((ext_vector_type(4))) float f32x4;

#define S_SEQ  2048
#define HID    1024
#define OUT3   3072
#define NROWS  4096
#define PSTR   72     // P-region row stride (bf16): 144B, 4-bank rotate

#if __has_builtin(__builtin_amdgcn_exp2f)
#define EXP2F(x) __builtin_amdgcn_exp2f(x)
#else
#define EXP2F(x) exp2f(x)
#endif

// q pre-scale: (1/sqrt(64)) * log2(e) -> scores in base-2 domain
#define QSCALE 0.18033688011112042f

// ---------------------------------------------------------------------------
// Fused cast: fp32 -> bf16 for X (2048 blocks) then W (1536 blocks).
// ---------------------------------------------------------------------------
__global__ __launch_bounds__(256) void cast_both_kernel(
    const float* __restrict__ X, bfr* __restrict__ Xb,
    const float* __restrict__ W, bfr* __restrict__ Wb)
{
    int bid = blockIdx.x;
    const float* src;
    bfr* dst;
    int lid;
    if (bid < NROWS * HID / 2048) { src = X; dst = Xb; lid = bid; }
    else { src = W; dst = Wb; lid = bid - NROWS * HID / 2048; }
    int gid = lid * 256 + threadIdx.x;
    const float4* s4 = (const float4*)src;
    float4 a = s4[(size_t)gid * 2];
    float4 b = s4[(size_t)gid * 2 + 1];
    bf16x8 v;
    v[0] = (bfr)a.x; v[1] = (bfr)a.y; v[2] = (bfr)a.z; v[3] = (bfr)a.w;
    v[4] = (bfr)b.x; v[5] = (bfr)b.y; v[6] = (bfr)b.z; v[7] = (bfr)b.w;
    *(bf16x8*)(dst + (size_t)gid * 8) = v;
}

// ---------------------------------------------------------------------------
// MFMA GEMM (m97 recipe, unchanged from R8). Epilogue splits into
// qb (pre-scaled by QSCALE), kb, vtb.
// ---------------------------------------------------------------------------
__device__ __forceinline__ void gload_lds16(const void* g, void* l) {
    __builtin_amdgcn_global_load_lds(
        (const __attribute__((address_space(1))) unsigned int*)g,
        (__attribute__((address_space(3))) unsigned int*)l, 16, 0, 0);
}

__global__ __launch_bounds__(256, 3) void qkv_gemm_mfma(
    const bfr* __restrict__ Xb, const bfr* __restrict__ Wb,
    const float* __restrict__ bias,
    bfr* __restrict__ qb, bfr* __restrict__ kb, bfr* __restrict__ vtb)
{
    __shared__ __attribute__((aligned(16))) bfr As[128 * 64];
    __shared__ __attribute__((aligned(16))) bfr Bs[128 * 64];

    const int o0 = blockIdx.x * 128;
    const int r0 = blockIdx.y * 128;
    const int tid = threadIdx.x;
    const int lane = tid & 63;
    const int w = tid >> 6;
    const int l15 = lane & 15;
    const int quad = lane >> 4;
    const int m0 = (w & 1) * 64;
    const int n0 = (w >> 1) * 64;

    f32x4 acc[4][4];
#pragma unroll
    for (int mi = 0; mi < 4; mi++)
#pragma unroll
        for (int ni = 0; ni < 4; ni++) acc[mi][ni] = {0.f, 0.f, 0.f, 0.f};

    for (int k0 = 0; k0 < HID; k0 += 64) {
#pragma unroll
        for (int i = 0; i < 4; i++) {
            int c = i * 256 + tid;
            int row = c >> 3, c8 = c & 7;
            gload_lds16(Xb + (size_t)(r0 + row) * HID + k0 + c8 * 8, As + c * 8);
            gload_lds16(Wb + (size_t)(o0 + row) * HID + k0 + c8 * 8, Bs + c * 8);
        }
        __syncthreads();

#pragma unroll
        for (int ks = 0; ks < 2; ks++) {
            bf16x8 af[4], bfg[4];
#pragma unroll
            for (int mi = 0; mi < 4; mi++)
                af[mi] = *(const bf16x8*)(As + (m0 + mi * 16 + l15) * 64 + ks * 32 + quad * 8);
#pragma unroll
            for (int ni = 0; ni < 4; ni++)
                bfg[ni] = *(const bf16x8*)(Bs + (n0 + ni * 16 + l15) * 64 + ks * 32 + quad * 8);
#pragma unroll
            for (int mi = 0; mi < 4; mi++)
#pragma unroll
                for (int ni = 0; ni < 4; ni++)
                    acc[mi][ni] = __builtin_amdgcn_mfma_f32_16x16x32_bf16(
                        af[mi], bfg[ni], acc[mi][ni], 0, 0, 0);
        }
        __syncthreads();
    }

#pragma unroll
    for (int ni = 0; ni < 4; ni++) {
        int cb = o0 + n0 + ni * 16;
        int h = cb / 192;
        int rem = cb % 192;
        int t = rem >> 6;
        int d = (rem & 63) + l15;
        float bv = bias[cb + l15];
#pragma unroll
        for (int mi = 0; mi < 4; mi++) {
#pragma unroll
            for (int r = 0; r < 4; r++) {
                int gr = r0 + m0 + mi * 16 + quad * 4 + r;
                int s = gr >> 1, b = gr & 1;
                int hb = h * 2 + b;
                float val = acc[mi][ni][r] + bv;
                if (t == 0)
                    qb[((size_t)hb * S_SEQ + s) * 64 + d] = (bfr)(val * QSCALE);
                else if (t == 1)
                    kb[((size_t)hb * S_SEQ + s) * 64 + d] = (bfr)val;
                else
                    vtb[((size_t)hb * 64 + d) * S_SEQ + s] = (bfr)val;
            }
        }
    }
}

// ---------------------------------------------------------------------------
// Attention R9: block = (32-q tile, hb); wave w owns keys [512w, 512w+512).
// No sync in the k-loop; K/V frags global->reg; LDS = P transpose + merge.
// Layouts (verified R4-R8): A[m=l15][k=quad*8+j], B[k=quad*8+j][n=l15],
// C/D col=l15(n), row=quad*4+reg(m).
// ---------------------------------------------------------------------------
__global__ __launch_bounds__(256, 4) void attn5_kernel(
    const bfr* __restrict__ qb, const bfr* __restrict__ kb,
    const bfr* __restrict__ vtb, float* __restrict__ out)
{
    // Union: during k-loop = 4 wave-private P regions (4*32*PSTR*2 = 18432B);
    // after barrier = Osum[4][64][33] f32 (33792B).
    __shared__ __attribute__((aligned(16))) unsigned char lds_raw[4 * 64 * 33 * 4];
    __shared__ float Lp[4][32];

    const int qt = blockIdx.x;          // 0..63 (32-row q tiles)
    const int hb = blockIdx.y;          // h*2+b
    const int h = hb >> 1, b = hb & 1;
    const int tid = threadIdx.x;
    const int lane = tid & 63;
    const int w = tid >> 6;
    const int l15 = lane & 15;
    const int quad = lane >> 4;
    const size_t hboff = (size_t)hb * S_SEQ * 64;

    bfr* Ptq = (bfr*)lds_raw + (size_t)w * 32 * PSTR;   // wave-private
    float* Osum = (float*)lds_raw;

    // Q fragments (B-operand), 2 n-tiles x 2 k-steps, loaded once.
    bf16x8 qf[2][2];
#pragma unroll
    for (int nt = 0; nt < 2; nt++)
#pragma unroll
        for (int ks = 0; ks < 2; ks++)
            qf[nt][ks] = *(const bf16x8*)(qb + hboff +
                (size_t)(qt * 32 + nt * 16 + l15) * 64 + quad * 8 + 32 * ks);

    f32x4 O[4][2];   // [mt=d-tile][nt=q-tile]
#pragma unroll
    for (int mt = 0; mt < 4; mt++)
#pragma unroll
        for (int nt = 0; nt < 2; nt++) O[mt][nt] = {0.f, 0.f, 0.f, 0.f};
    float lsum[2] = {0.f, 0.f};

    for (int kt = 0; kt < 8; kt++) {
        const int kb0 = w * 512 + kt * 64;

        // --- S^T = K Q^T: K frags direct from global (A-operand pattern) ---
        f32x4 sc[4][2];
#pragma unroll
        for (int mt = 0; mt < 4; mt++)
#pragma unroll
            for (int nt = 0; nt < 2; nt++) sc[mt][nt] = {0.f, 0.f, 0.f, 0.f};
#pragma unroll
        for (int ks = 0; ks < 2; ks++) {
            bf16x8 kf[4];
#pragma unroll
            for (int mt = 0; mt < 4; mt++)
                kf[mt] = *(const bf16x8*)(kb + hboff +
                    (size_t)(kb0 + mt * 16 + l15) * 64 + quad * 8 + 32 * ks);
#pragma unroll
            for (int mt = 0; mt < 4; mt++)
#pragma unroll
                for (int nt = 0; nt < 2; nt++)
                    sc[mt][nt] = __builtin_amdgcn_mfma_f32_16x16x32_bf16(
                        kf[mt], qf[nt][ks], sc[mt][nt], 0, 0, 0);
        }

        // --- p = 2^s; accumulate l; pack P^T (q-major) to wave-private LDS ---
#pragma unroll
        for (int nt = 0; nt < 2; nt++) {
#pragma unroll
            for (int mt = 0; mt < 4; mt++) {
                bf16x4 pk;
#pragma unroll
                for (int r = 0; r < 4; r++) {
                    float pv = EXP2F(sc[mt][nt][r]);
                    lsum[nt] += pv;
                    pk[r] = (bfr)pv;
                }
                *(bf16x4*)(Ptq + (nt * 16 + l15) * PSTR + mt * 16 + quad * 4) = pk;
            }
        }

        // --- O^T += V^T P^T: V frags direct from global ---
#pragma unroll
        for (int ks = 0; ks < 2; ks++) {
            bf16x8 vf[4], pf[2];
#pragma unroll
            for (int mt = 0; mt < 4; mt++)
                vf[mt] = *(const bf16x8*)(vtb + hboff +
                    (size_t)(mt * 16 + l15) * S_SEQ + kb0 + quad * 8 + 32 * ks);
#pragma unroll
            for (int nt = 0; nt < 2; nt++)
                pf[nt] = *(const bf16x8*)(Ptq + (nt * 16 + l15) * PSTR + quad * 8 + 32 * ks);
#pragma unroll
            for (int mt = 0; mt < 4; mt++)
#pragma unroll
                for (int nt = 0; nt < 2; nt++)
                    O[mt][nt] = __builtin_amdgcn_mfma_f32_16x16x32_bf16(
                        vf[mt], pf[nt], O[mt][nt], 0, 0, 0);
        }
    }

    // --- finalize per-wave l (sum across quads = key groups) ---
#pragma unroll
    for (int nt = 0; nt < 2; nt++) {
        lsum[nt] += __shfl_xor(lsum[nt], 16);
        lsum[nt] += __shfl_xor(lsum[nt], 32);
    }
    if (quad == 0) { Lp[w][l15] = lsum[0]; Lp[w][16 + l15] = lsum[1]; }

    __syncthreads();   // all waves done with P regions; safe to clobber with Osum

    // --- write per-wave O partial: Osum[w][d][q] ---
#pragma unroll
    for (int mt = 0; mt < 4; mt++)
#pragma unroll
        for (int nt = 0; nt < 2; nt++)
#pragma unroll
            for (int r = 0; r < 4; r++)
                Osum[((size_t)w * 64 + mt * 16 + quad * 4 + r) * 33 + nt * 16 + l15]
                    = O[mt][nt][r];

    __syncthreads();

    // --- merge: wave w handles d = w*16 + l15, q = quad + 4i ---
    {
        const int d = w * 16 + l15;
#pragma unroll
        for (int i = 0; i < 8; i++) {
            int q = quad + 4 * i;
            float acc = 0.f;
#pragma unroll
            for (int wv = 0; wv < 4; wv++)
                acc += Osum[((size_t)wv * 64 + d) * 33 + q];
            float lt = Lp[0][q] + Lp[1][q] + Lp[2][q] + Lp[3][q];
            int s = qt * 32 + q;
            out[((size_t)s * 2 + b) * HID + h * 64 + d] = acc / lt;
        }
    }
}

// ---------------------------------------------------------------------------
extern "C" void kernel_launch(void* const* d_in, const int* in_sizes, int n_in,
                              void* d_out, int out_size, void* d_ws, size_t ws_size,
                              hipStream_t stream) {
    const float* X    = (const float*)d_in[0];
    const float* W    = (const float*)d_in[1];
    const float* bias = (const float*)d_in[2];
    float* out = (float*)d_out;

    bfr* qb  = (bfr*)d_ws;
    bfr* kb  = qb + (size_t)32 * S_SEQ * 64;
    bfr* vtb = kb + (size_t)32 * S_SEQ * 64;

    // d_out as cast scratch (14.7 MB <= 16.8 MB); attention overwrites it last.
    bfr* Xb = (bfr*)d_out;
    bfr* Wb = Xb + (size_t)NROWS * HID;

    cast_both_kernel<<<(NROWS * HID + OUT3 * HID) / 2048, 256, 0, stream>>>(X, Xb, W, Wb);

    dim3 g1(OUT3 / 128, NROWS / 128);
    qkv_gemm_mfma<<<g1, 256, 0, stream>>>(Xb, Wb, bias, qb, kb, vtb);

    dim3 g2(S_SEQ / 32, 32);                    // 64 x 32 = 2048 blocks
    attn5_kernel<<<g2, 256, 0, stream>>>(qb, kb, vtb, out);
}

// Round 10
// 225.613 us; speedup vs baseline: 1.0457x; 1.0457x over previous
//
#include <hip/hip_runtime.h>
#include <hip/hip_bf16.h>

// Fused QKV projection + 16-head self-attention. S=2048, B=2, H=1024, NH=16, DH=64.
// Inputs fp32, output fp32. bf16 internal compute (2% rel threshold).
//
// R10: key-split attention, staged. R9 (direct-global, no barriers) was
// latency-bound (MfmaUtil 10.6, VALUBusy 14.9 — both idle). Keep R8's
// staged+barrier skeleton; split KEYS across waves (linear no-max softmax
// partials; merge once at end). K staged via async global_load_lds; V frags
// global->reg issued BEFORE the staging barrier (latency drains with K).
// P transpose wave-private by column. LDS/64keys: 96KB (R8) -> ~32KB.
//
// d_ws: qb[hb][s][d] 8MB | kb[hb][s][d] 8MB | vtb[hb][d][s] 8MB  (hb = h*2+b)

typedef __hip_bfloat16 bf16;
typedef __bf16 bfr;
typedef __attribute__((ext_vector_type(8))) __bf16 bf16x8;
typedef __attribute__((ext_vector_type(4))) __bf16 bf16x4;
typedef __attribute__((ext_vector_type(4))) float f32x4;

#define S_SEQ  2048
#define HID    1024
#define OUT3   3072
#define NROWS  4096
#define PSTR   136    // P region row stride (bf16 elems): 272B = 4-bank rotate

#if __has_builtin(__builtin_amdgcn_exp2f)
#define EXP2F(x) __builtin_amdgcn_exp2f(x)
#else
#define EXP2F(x) exp2f(x)
#endif

// q pre-scale: (1/sqrt(64)) * log2(e) -> scores in base-2 domain
#define QSCALE 0.18033688011112042f

// ---------------------------------------------------------------------------
// Fused cast: fp32 -> bf16 for X then W.
// ---------------------------------------------------------------------------
__global__ __launch_bounds__(256) void cast_both_kernel(
    const float* __restrict__ X, bfr* __restrict__ Xb,
    const float* __restrict__ W, bfr* __restrict__ Wb)
{
    int bid = blockIdx.x;
    const float* src;
    bfr* dst;
    int lid;
    if (bid < NROWS * HID / 2048) { src = X; dst = Xb; lid = bid; }
    else { src = W; dst = Wb; lid = bid - NROWS * HID / 2048; }
    int gid = lid * 256 + threadIdx.x;
    const float4* s4 = (const float4*)src;
    float4 a = s4[(size_t)gid * 2];
    float4 b = s4[(size_t)gid * 2 + 1];
    bf16x8 v;
    v[0] = (bfr)a.x; v[1] = (bfr)a.y; v[2] = (bfr)a.z; v[3] = (bfr)a.w;
    v[4] = (bfr)b.x; v[5] = (bfr)b.y; v[6] = (bfr)b.z; v[7] = (bfr)b.w;
    *(bf16x8*)(dst + (size_t)gid * 8) = v;
}

// ---------------------------------------------------------------------------
// MFMA GEMM (m97 recipe, unchanged from R8). Epilogue splits into
// qb (pre-scaled by QSCALE), kb, vtb.
// ---------------------------------------------------------------------------
__device__ __forceinline__ void gload_lds16(const void* g, void* l) {
    __builtin_amdgcn_global_load_lds(
        (const __attribute__((address_space(1))) unsigned int*)g,
        (__attribute__((address_space(3))) unsigned int*)l, 16, 0, 0);
}

__global__ __launch_bounds__(256, 3) void qkv_gemm_mfma(
    const bfr* __restrict__ Xb, const bfr* __restrict__ Wb,
    const float* __restrict__ bias,
    bfr* __restrict__ qb, bfr* __restrict__ kb, bfr* __restrict__ vtb)
{
    __shared__ __attribute__((aligned(16))) bfr As[128 * 64];
    __shared__ __attribute__((aligned(16))) bfr Bs[128 * 64];

    const int o0 = blockIdx.x * 128;
    const int r0 = blockIdx.y * 128;
    const int tid = threadIdx.x;
    const int lane = tid & 63;
    const int w = tid >> 6;
    const int l15 = lane & 15;
    const int quad = lane >> 4;
    const int m0 = (w & 1) * 64;
    const int n0 = (w >> 1) * 64;

    f32x4 acc[4][4];
#pragma unroll
    for (int mi = 0; mi < 4; mi++)
#pragma unroll
        for (int ni = 0; ni < 4; ni++) acc[mi][ni] = {0.f, 0.f, 0.f, 0.f};

    for (int k0 = 0; k0 < HID; k0 += 64) {
#pragma unroll
        for (int i = 0; i < 4; i++) {
            int c = i * 256 + tid;
            int row = c >> 3, c8 = c & 7;
            gload_lds16(Xb + (size_t)(r0 + row) * HID + k0 + c8 * 8, As + c * 8);
            gload_lds16(Wb + (size_t)(o0 + row) * HID + k0 + c8 * 8, Bs + c * 8);
        }
        __syncthreads();

#pragma unroll
        for (int ks = 0; ks < 2; ks++) {
            bf16x8 af[4], bfg[4];
#pragma unroll
            for (int mi = 0; mi < 4; mi++)
                af[mi] = *(const bf16x8*)(As + (m0 + mi * 16 + l15) * 64 + ks * 32 + quad * 8);
#pragma unroll
            for (int ni = 0; ni < 4; ni++)
                bfg[ni] = *(const bf16x8*)(Bs + (n0 + ni * 16 + l15) * 64 + ks * 32 + quad * 8);
#pragma unroll
            for (int mi = 0; mi < 4; mi++)
#pragma unroll
                for (int ni = 0; ni < 4; ni++)
                    acc[mi][ni] = __builtin_amdgcn_mfma_f32_16x16x32_bf16(
                        af[mi], bfg[ni], acc[mi][ni], 0, 0, 0);
        }
        __syncthreads();
    }

#pragma unroll
    for (int ni = 0; ni < 4; ni++) {
        int cb = o0 + n0 + ni * 16;
        int h = cb / 192;
        int rem = cb % 192;
        int t = rem >> 6;
        int d = (rem & 63) + l15;
        float bv = bias[cb + l15];
#pragma unroll
        for (int mi = 0; mi < 4; mi++) {
#pragma unroll
            for (int r = 0; r < 4; r++) {
                int gr = r0 + m0 + mi * 16 + quad * 4 + r;
                int s = gr >> 1, b = gr & 1;
                int hb = h * 2 + b;
                float val = acc[mi][ni][r] + bv;
                if (t == 0)
                    qb[((size_t)hb * S_SEQ + s) * 64 + d] = (bfr)(val * QSCALE);
                else if (t == 1)
                    kb[((size_t)hb * S_SEQ + s) * 64 + d] = (bfr)val;
                else
                    vtb[((size_t)hb * 64 + d) * S_SEQ + s] = (bfr)val;
            }
        }
    }
}

// ---------------------------------------------------------------------------
// Attention R10: block = (64-q tile, hb), 4 waves. Super-tile = 128 keys;
// wave w owns keys [32w, 32w+32): S (2mt x 4nt x 2ks = 16 mfma) and
// PV (4mt x 4nt, K=32 = 16 mfma) over its keys only; O/l merged at end.
// K staged to LDS via global_load_lds (unpadded, m97-style); V frags
// global->reg issued before the staging barrier. P wave-private by column.
// Layouts (verified R4-R9): A[m=l15][k=quad*8+j], B[k=quad*8+j][n=l15],
// C/D col=l15(n), row=quad*4+reg(m).
// ---------------------------------------------------------------------------
__global__ __launch_bounds__(256, 3) void attn6_kernel(
    const bfr* __restrict__ qb, const bfr* __restrict__ kb,
    const bfr* __restrict__ vtb, float* __restrict__ out)
{
    // [0, 16384): Ks 128x64 bf16 unpadded (global_load_lds dest) / merge buf0
    // [16384, 16384+17408): Pq 64 x PSTR bf16 / merge buf1
    __shared__ __attribute__((aligned(16))) unsigned char lds_raw[16384 + 17408];
    __shared__ float Lp[4][64];

    bfr* Ks = (bfr*)lds_raw;
    bfr* Pq = (bfr*)(lds_raw + 16384);

    const int qt = blockIdx.x;          // 0..31 (64-row q tiles)
    const int hb = blockIdx.y;          // h*2+b
    const int h = hb >> 1, b = hb & 1;
    const int tid = threadIdx.x;
    const int lane = tid & 63;
    const int w = tid >> 6;
    const int l15 = lane & 15;
    const int quad = lane >> 4;
    const size_t hboff = (size_t)hb * S_SEQ * 64;

    // Q fragments (B-operand), all 4 n-tiles x 2 k-steps, loaded once.
    bf16x8 qf[4][2];
#pragma unroll
    for (int nt = 0; nt < 4; nt++)
#pragma unroll
        for (int ks = 0; ks < 2; ks++)
            qf[nt][ks] = *(const bf16x8*)(qb + hboff +
                (size_t)(qt * 64 + nt * 16 + l15) * 64 + quad * 8 + 32 * ks);

    f32x4 O[4][4];   // [mt=d-tile][nt=q-tile], partial over wave's keys
#pragma unroll
    for (int mt = 0; mt < 4; mt++)
#pragma unroll
        for (int nt = 0; nt < 4; nt++) O[mt][nt] = {0.f, 0.f, 0.f, 0.f};
    float lsum[4] = {0.f, 0.f, 0.f, 0.f};

    for (int kt = 0; kt < 16; kt++) {
        __syncthreads();   // previous iteration done reading Ks
        // --- stage K (128 keys x 64 d) async to LDS ---
#pragma unroll
        for (int i = 0; i < 4; i++) {
            int c = i * 256 + tid;          // 0..1023 16B chunks
            int row = c >> 3, c8 = c & 7;
            gload_lds16(kb + hboff + (size_t)(kt * 128 + row) * 64 + c8 * 8, Ks + c * 8);
        }
        // --- V^T fragments for this wave's 32 keys, direct global->reg;
        //     issued before the barrier so latency drains with K staging ---
        bf16x8 vf[4];
#pragma unroll
        for (int mt = 0; mt < 4; mt++)
            vf[mt] = *(const bf16x8*)(vtb + hboff +
                (size_t)(mt * 16 + l15) * S_SEQ + kt * 128 + 32 * w + quad * 8);
        __syncthreads();   // staging visible (vmcnt drained)

        // --- S^T = K Q^T over wave's keys [32w, 32w+32) ---
        f32x4 sc[2][4];
#pragma unroll
        for (int mt = 0; mt < 2; mt++)
#pragma unroll
            for (int nt = 0; nt < 4; nt++) sc[mt][nt] = {0.f, 0.f, 0.f, 0.f};
#pragma unroll
        for (int ks = 0; ks < 2; ks++) {
            bf16x8 kf[2];
#pragma unroll
            for (int mt = 0; mt < 2; mt++)
                kf[mt] = *(const bf16x8*)(Ks + (32 * w + mt * 16 + l15) * 64 + quad * 8 + 32 * ks);
#pragma unroll
            for (int mt = 0; mt < 2; mt++)
#pragma unroll
                for (int nt = 0; nt < 4; nt++)
                    sc[mt][nt] = __builtin_amdgcn_mfma_f32_16x16x32_bf16(
                        kf[mt], qf[nt][ks], sc[mt][nt], 0, 0, 0);
        }

        // --- p = 2^s; accumulate l; pack P^T[q][key] (wave-private columns) ---
#pragma unroll
        for (int nt = 0; nt < 4; nt++) {
#pragma unroll
            for (int mt = 0; mt < 2; mt++) {
                bf16x4 pk;
#pragma unroll
                for (int r = 0; r < 4; r++) {
                    float pv = EXP2F(sc[mt][nt][r]);
                    lsum[nt] += pv;
                    pk[r] = (bfr)pv;
                }
                *(bf16x4*)(Pq + (nt * 16 + l15) * PSTR + 32 * w + mt * 16 + quad * 4) = pk;
            }
        }

        // --- O^T += V^T P^T (K=32 = wave's keys; P columns wave-private) ---
        bf16x8 pf[4];
#pragma unroll
        for (int nt = 0; nt < 4; nt++)
            pf[nt] = *(const bf16x8*)(Pq + (nt * 16 + l15) * PSTR + 32 * w + quad * 8);
#pragma unroll
        for (int mt = 0; mt < 4; mt++)
#pragma unroll
            for (int nt = 0; nt < 4; nt++)
                O[mt][nt] = __builtin_amdgcn_mfma_f32_16x16x32_bf16(
                    vf[mt], pf[nt], O[mt][nt], 0, 0, 0);
    }

    // --- per-wave l totals (sum over quads = key groups within wave) ---
#pragma unroll
    for (int nt = 0; nt < 4; nt++) {
        lsum[nt] += __shfl_xor(lsum[nt], 16);
        lsum[nt] += __shfl_xor(lsum[nt], 32);
        if (quad == 0) Lp[w][nt * 16 + l15] = lsum[nt];
    }
    __syncthreads();   // all waves done with Ks/Pq reads; Lp visible

    // --- merge O partials across waves (tree via LDS, f32x4 lanes) ---
    f32x4* m0 = (f32x4*)lds_raw;            // 16 KB (Ks region)
    f32x4* m1 = (f32x4*)(lds_raw + 16384);  // 16 KB (Pq region)
    if (w == 1) {
#pragma unroll
        for (int mt = 0; mt < 4; mt++)
#pragma unroll
            for (int nt = 0; nt < 4; nt++) m0[(mt * 4 + nt) * 64 + lane] = O[mt][nt];
    }
    if (w == 3) {
#pragma unroll
        for (int mt = 0; mt < 4; mt++)
#pragma unroll
            for (int nt = 0; nt < 4; nt++) m1[(mt * 4 + nt) * 64 + lane] = O[mt][nt];
    }
    __syncthreads();
    if (w == 0) {
#pragma unroll
        for (int mt = 0; mt < 4; mt++)
#pragma unroll
            for (int nt = 0; nt < 4; nt++) O[mt][nt] += m0[(mt * 4 + nt) * 64 + lane];
    }
    if (w == 2) {
#pragma unroll
        for (int mt = 0; mt < 4; mt++)
#pragma unroll
            for (int nt = 0; nt < 4; nt++) O[mt][nt] += m1[(mt * 4 + nt) * 64 + lane];
    }
    __syncthreads();
    if (w == 2) {
#pragma unroll
        for (int mt = 0; mt < 4; mt++)
#pragma unroll
            for (int nt = 0; nt < 4; nt++) m0[(mt * 4 + nt) * 64 + lane] = O[mt][nt];
    }
    __syncthreads();
    if (w == 0) {
        // final add + normalize + store (O value at d=mt*16+quad*4+r, q=nt*16+l15)
#pragma unroll
        for (int nt = 0; nt < 4; nt++) {
            int q = nt * 16 + l15;
            float lt = Lp[0][q] + Lp[1][q] + Lp[2][q] + Lp[3][q];
            float inv = 1.0f / lt;
            int s = qt * 64 + q;
            float* orow = out + ((size_t)s * 2 + b) * HID + h * 64;
#pragma unroll
            for (int mt = 0; mt < 4; mt++) {
                f32x4 v = O[mt][nt] + m0[(mt * 4 + nt) * 64 + lane];
                float4 o4;
                o4.x = v[0] * inv; o4.y = v[1] * inv;
                o4.z = v[2] * inv; o4.w = v[3] * inv;
                *(float4*)(orow + mt * 16 + quad * 4) = o4;
            }
        }
    }
}

// ---------------------------------------------------------------------------
extern "C" void kernel_launch(void* const* d_in, const int* in_sizes, int n_in,
                              void* d_out, int out_size, void* d_ws, size_t ws_size,
                              hipStream_t stream) {
    const float* X    = (const float*)d_in[0];
    const float* W    = (const float*)d_in[1];
    const float* bias = (const float*)d_in[2];
    float* out = (float*)d_out;

    bfr* qb  = (bfr*)d_ws;
    bfr* kb  = qb + (size_t)32 * S_SEQ * 64;
    bfr* vtb = kb + (size_t)32 * S_SEQ * 64;

    // d_out as cast scratch (14.7 MB <= 16.8 MB); attention overwrites it last.
    bfr* Xb = (bfr*)d_out;
    bfr* Wb = Xb + (size_t)NROWS * HID;

    cast_both_kernel<<<(NROWS * HID + OUT3 * HID) / 2048, 256, 0, stream>>>(X, Xb, W, Wb);

    dim3 g1(OUT3 / 128, NROWS / 128);
    qkv_gemm_mfma<<<g1, 256, 0, stream>>>(Xb, Wb, bias, qb, kb, vtb);

    dim3 g2(S_SEQ / 64, 32);                    // 32 x 32 = 1024 blocks
    attn6_kernel<<<g2, 256, 0, stream>>>(qb, kb, vtb, out);
}